// Round 1
// baseline (4808.618 us; speedup 1.0000x reference)
//
#include <hip/hip_runtime.h>
#include <hip/hip_bf16.h>
#include <stdint.h>

#define Bb 32
#define Tt 512
#define Dd 1024
#define Hh 1024
#define Cc 1000
#define Mm (Bb*Tt)

typedef float f32x4 __attribute__((ext_vector_type(4)));
typedef short bf16x8 __attribute__((ext_vector_type(8)));

#define MFMA16(a,b,c) __builtin_amdgcn_mfma_f32_16x16x32_bf16(a,b,c,0,0,0)

static __device__ __forceinline__ unsigned short f2b(float f){
  __hip_bfloat16 h = __float2bfloat16(f);
  union { __hip_bfloat16 h; unsigned short u; } cv; cv.h = h; return cv.u;
}
static __device__ __forceinline__ float b2f(unsigned short u){
  union { unsigned int i; float f; } cv; cv.i = ((unsigned int)u) << 16; return cv.f;
}

static __device__ __forceinline__ void async16(const ushort* g, ushort* l){
  __builtin_amdgcn_global_load_lds((const __attribute__((address_space(1))) unsigned int*)g,
                                   (__attribute__((address_space(3))) unsigned int*)l,
                                   16, 0, 0);
}

// ---------------- conversion kernels ----------------

__global__ void cvt_bf16(const float* __restrict__ in, ushort* __restrict__ out, int n4){
  int i = blockIdx.x*256 + threadIdx.x;
  if (i < n4){
    const float4 v = ((const float4*)in)[i];
    ushort4 o;
    o.x = f2b(v.x); o.y = f2b(v.y); o.z = f2b(v.z); o.w = f2b(v.w);
    ((ushort4*)out)[i] = o;
  }
}

// pad W2 [1000][1024] -> bf16 [1024][1024] (zero rows >=1000); pad b2 -> 1024 fp32
__global__ void pad_w2(const float* __restrict__ w2, const float* __restrict__ b2,
                       ushort* __restrict__ w2p, float* __restrict__ b2p){
  int i = blockIdx.x*256 + threadIdx.x;          // 0 .. 1048575
  int r = i >> 10, c = i & 1023;
  w2p[i] = (r < Cc) ? f2b(w2[r*1024 + c]) : (ushort)0;
  if (i < 1024) b2p[i] = (i < Cc) ? b2[i] : 0.f;
}

// ---------------- generic bf16 MFMA GEMM: C[M,N] = op(A[M,K] * B[N,K]^T + bias) ----------------
// 128x128 tile, BK=32, 4 waves (2x2), each wave 64x64 (4x4 fragments of 16x16x32)

template<int RELU, int OUT_BF16>
__global__ __launch_bounds__(256) void gemm_bt(
    const ushort* __restrict__ A, const ushort* __restrict__ Bm,
    const float* __restrict__ bias, void* __restrict__ Cp,
    int M, int N, int K, int ldc, int nout)
{
  __shared__ ushort As[128*32];
  __shared__ ushort Bs[128*32];
  const int tid  = threadIdx.x;
  const int lane = tid & 63;
  const int wave = tid >> 6;
  const int wr = wave >> 1, wc = wave & 1;
  const int r0 = lane & 15, kg = lane >> 4;
  const int m0 = blockIdx.x*128, n0 = blockIdx.y*128;

  const ushort* aG = A  + (size_t)(m0 + (tid>>2))*K + (tid&3)*8;
  const ushort* bG = Bm + (size_t)(n0 + (tid>>2))*K + (tid&3)*8;
  ushort* aL = As + tid*8;
  ushort* bL = Bs + tid*8;
  const size_t rstep = (size_t)64*K;

  f32x4 acc[4][4] = {};

  for (int kt = 0; kt < K; kt += 32){
    __syncthreads();
    async16(aG + kt,         aL);
    async16(aG + kt + rstep, aL + 2048);
    async16(bG + kt,         bL);
    async16(bG + kt + rstep, bL + 2048);
    __syncthreads();
    bf16x8 af[4], bf_[4];
#pragma unroll
    for (int i=0;i<4;i++) af[i]  = *(const bf16x8*)&As[(wr*64 + i*16 + r0)*32 + kg*8];
#pragma unroll
    for (int j=0;j<4;j++) bf_[j] = *(const bf16x8*)&Bs[(wc*64 + j*16 + r0)*32 + kg*8];
#pragma unroll
    for (int i=0;i<4;i++)
#pragma unroll
      for (int j=0;j<4;j++)
        acc[i][j] = MFMA16(af[i], bf_[j], acc[i][j]);
  }

  const int rowb = m0 + wr*64 + kg*4;
  const int colb = n0 + wc*64 + r0;
#pragma unroll
  for (int i=0;i<4;i++){
#pragma unroll
    for (int j=0;j<4;j++){
      const int c = colb + j*16;
      if (c >= nout) continue;
      const float bv = bias ? bias[c] : 0.f;
#pragma unroll
      for (int q=0;q<4;q++){
        const int r = rowb + i*16 + q;
        float v = acc[i][j][q] + bv;
        if (RELU) v = fmaxf(v, 0.f);
        if (OUT_BF16) ((ushort*)Cp)[(size_t)r*ldc + c] = f2b(v);
        else          ((float* )Cp)[(size_t)r*ldc + c] = v;
      }
    }
  }
}

// ---------------- GRU step ----------------
// grid 64 WGs; WG g owns hidden units [g*16, g*16+16).
// GEMM: gh[32 x 48] = h[32 x 1024] * Whh_rows^T, K split over 4 waves, LDS reduce.
// Then fused gate elementwise; h ping-pong (fp32 carry + bf16 for next MFMA).

__global__ __launch_bounds__(256) void gru_step(
    const ushort* __restrict__ Whh, const float* __restrict__ bhh,
    const ushort* __restrict__ gx,
    const float* __restrict__ hinf, const ushort* __restrict__ hinb,
    float* __restrict__ houtf, ushort* __restrict__ houtb,
    ushort* __restrict__ hs, int t)
{
  __shared__ float red[4][2][3][256];
  const int g = blockIdx.x;
  const int tid = threadIdx.x;
  const int wave = tid >> 6, lane = tid & 63;
  const int r0 = lane & 15, kg = lane >> 4;
  f32x4 acc[2][3] = {};
  const int k0 = wave*256 + kg*8;
  const ushort* aB = hinb + r0*1024 + k0;
  const ushort* bB = Whh + ((size_t)(g*16 + r0))*1024 + k0;
#pragma unroll
  for (int s=0; s<8; ++s){
    const int kk = s*32;
    bf16x8 a0  = *(const bf16x8*)(aB + kk);
    bf16x8 a1  = *(const bf16x8*)(aB + 16*1024 + kk);
    bf16x8 b0  = *(const bf16x8*)(bB + kk);
    bf16x8 b1  = *(const bf16x8*)(bB + 1024*1024 + kk);
    bf16x8 b2v = *(const bf16x8*)(bB + 2*1024*1024 + kk);
    acc[0][0] = MFMA16(a0,b0, acc[0][0]);
    acc[0][1] = MFMA16(a0,b1, acc[0][1]);
    acc[0][2] = MFMA16(a0,b2v,acc[0][2]);
    acc[1][0] = MFMA16(a1,b0, acc[1][0]);
    acc[1][1] = MFMA16(a1,b1, acc[1][1]);
    acc[1][2] = MFMA16(a1,b2v,acc[1][2]);
  }
#pragma unroll
  for (int i=0;i<2;i++)
#pragma unroll
    for (int j=0;j<3;j++)
      *(f32x4*)&red[wave][i][j][lane*4] = acc[i][j];
  __syncthreads();

  for (int p = tid; p < 512; p += 256){
    const int b = p >> 4, u = p & 15;
    const int i = b >> 4, bi = b & 15;
    const int idx = ((bi>>2)*16 + u)*4 + (bi&3);
    float hr=0.f, hz=0.f, hn=0.f;
#pragma unroll
    for (int w4=0; w4<4; ++w4){
      hr += red[w4][i][0][idx];
      hz += red[w4][i][1][idx];
      hn += red[w4][i][2][idx];
    }
    const int jg = g*16 + u;
    hr += bhh[jg]; hz += bhh[1024+jg]; hn += bhh[2048+jg];
    const size_t row = (size_t)b*Tt + t;
    const float xr = b2f(gx[row*3072 + jg]);
    const float xz = b2f(gx[row*3072 + 1024 + jg]);
    const float xn = b2f(gx[row*3072 + 2048 + jg]);
    const float r = 1.f/(1.f + expf(-(xr+hr)));
    const float z = 1.f/(1.f + expf(-(xz+hz)));
    const float n = tanhf(xn + r*hn);
    const float hold = hinf[b*1024 + jg];
    const float hnew = (1.f - z)*n + z*hold;
    houtf[b*1024 + jg] = hnew;
    houtb[b*1024 + jg] = f2b(hnew);
    hs[row*1024 + jg] = f2b(hnew);
  }
}

// ---------------- launch ----------------

extern "C" void kernel_launch(void* const* d_in, const int* in_sizes, int n_in,
                              void* d_out, int out_size, void* d_ws, size_t ws_size,
                              hipStream_t stream)
{
  const float* features = (const float*)d_in[0];
  const float* Wp  = (const float*)d_in[1];
  const float* bp  = (const float*)d_in[2];
  const float* Wih = (const float*)d_in[3];
  const float* bih = (const float*)d_in[4];
  const float* Whh = (const float*)d_in[5];
  const float* bhh = (const float*)d_in[6];
  const float* W1  = (const float*)d_in[7];
  const float* b1  = (const float*)d_in[8];
  const float* W2  = (const float*)d_in[9];
  const float* b2  = (const float*)d_in[10];
  float* out = (float*)d_out;

  char* w = (char*)d_ws;
  auto alloc = [&](size_t bytes){ char* p = w; w += (bytes + 255) & ~(size_t)255; return p; };
  ushort* fb   = (ushort*)alloc((size_t)Mm*Dd*2);
  ushort* xb   = (ushort*)alloc((size_t)Mm*Hh*2);
  ushort* gx   = (ushort*)alloc((size_t)Mm*3*Hh*2);
  ushort* hsb  = (ushort*)alloc((size_t)Mm*Hh*2);
  ushort* o1   = (ushort*)alloc((size_t)Mm*Hh*2);
  ushort* wpb  = (ushort*)alloc((size_t)Hh*Dd*2);
  ushort* wihb = (ushort*)alloc((size_t)3*Hh*Hh*2);
  ushort* whhb = (ushort*)alloc((size_t)3*Hh*Hh*2);
  ushort* w1b  = (ushort*)alloc((size_t)Hh*Hh*2);
  ushort* w2b  = (ushort*)alloc((size_t)1024*Hh*2);
  float*  b2p  = (float*)alloc(1024*4);
  float*  hF   = (float*)alloc((size_t)2*Bb*Hh*4);
  ushort* hB   = (ushort*)alloc((size_t)2*Bb*Hh*2);

  hipMemsetAsync(hF, 0, (size_t)2*Bb*Hh*4, stream);
  hipMemsetAsync(hB, 0, (size_t)2*Bb*Hh*2, stream);

  auto cvt = [&](const float* src, ushort* dst, size_t n){
    int n4 = (int)(n/4);
    hipLaunchKernelGGL(cvt_bf16, dim3((n4+255)/256), dim3(256), 0, stream, src, dst, n4);
  };
  cvt(features, fb, (size_t)Mm*Dd);
  cvt(Wp,  wpb,  (size_t)Hh*Dd);
  cvt(Wih, wihb, (size_t)3*Hh*Hh);
  cvt(Whh, whhb, (size_t)3*Hh*Hh);
  cvt(W1,  w1b,  (size_t)Hh*Hh);
  hipLaunchKernelGGL(pad_w2, dim3((1024*1024)/256), dim3(256), 0, stream, W2, b2, w2b, b2p);

  // x = relu(features @ Wp^T + bp)
  hipLaunchKernelGGL((gemm_bt<1,1>), dim3(Mm/128, Hh/128), dim3(256), 0, stream,
                     fb, wpb, bp, (void*)xb, Mm, Hh, Dd, Hh, Hh);
  // gx = x @ W_ih^T + b_ih
  hipLaunchKernelGGL((gemm_bt<0,1>), dim3(Mm/128, (3*Hh)/128), dim3(256), 0, stream,
                     xb, wihb, bih, (void*)gx, Mm, 3*Hh, Hh, 3*Hh, 3*Hh);

  // GRU scan
  for (int t=0; t<Tt; ++t){
    const float*  hinf  = hF + (size_t)(t&1)*Bb*Hh;
    float*        houtf = hF + (size_t)((t+1)&1)*Bb*Hh;
    const ushort* hinb  = hB + (size_t)(t&1)*Bb*Hh;
    ushort*       houtb = hB + (size_t)((t+1)&1)*Bb*Hh;
    hipLaunchKernelGGL(gru_step, dim3(64), dim3(256), 0, stream,
                       whhb, bhh, gx, hinf, hinb, houtf, houtb, hsb, t);
  }

  // out1 = relu(hs @ W1^T + b1)
  hipLaunchKernelGGL((gemm_bt<1,1>), dim3(Mm/128, Hh/128), dim3(256), 0, stream,
                     hsb, w1b, b1, (void*)o1, Mm, Hh, Hh, Hh, Hh);
  // out = out1 @ W2p^T + b2p  (store only first 1000 cols, fp32)
  hipLaunchKernelGGL((gemm_bt<0,0>), dim3(Mm/128, 1024/128), dim3(256), 0, stream,
                     o1, w2b, b2p, (void*)out, Mm, 1024, Hh, Cc, Cc);
}

// Round 2
// 4626.728 us; speedup vs baseline: 1.0393x; 1.0393x over previous
//
#include <hip/hip_runtime.h>
#include <hip/hip_bf16.h>
#include <stdint.h>

#define Bb 32
#define Tt 512
#define Dd 1024
#define Hh 1024
#define Cc 1000
#define Mm (Bb*Tt)
#define NWG 64

typedef float f32x4 __attribute__((ext_vector_type(4)));
typedef short bf16x8 __attribute__((ext_vector_type(8)));

#define MFMA16(a,b,c) __builtin_amdgcn_mfma_f32_16x16x32_bf16(a,b,c,0,0,0)

static __device__ __forceinline__ unsigned short f2b(float f){
  __hip_bfloat16 h = __float2bfloat16(f);
  union { __hip_bfloat16 h; unsigned short u; } cv; cv.h = h; return cv.u;
}
static __device__ __forceinline__ float b2f(unsigned short u){
  union { unsigned int i; float f; } cv; cv.i = ((unsigned int)u) << 16; return cv.f;
}

static __device__ __forceinline__ void async16(const ushort* g, ushort* l){
  __builtin_amdgcn_global_load_lds((const __attribute__((address_space(1))) unsigned int*)g,
                                   (__attribute__((address_space(3))) unsigned int*)l,
                                   16, 0, 0);
}

// ---------------- conversion kernels ----------------

__global__ void cvt_bf16(const float* __restrict__ in, ushort* __restrict__ out, int n4){
  int i = blockIdx.x*256 + threadIdx.x;
  if (i < n4){
    const float4 v = ((const float4*)in)[i];
    ushort4 o;
    o.x = f2b(v.x); o.y = f2b(v.y); o.z = f2b(v.z); o.w = f2b(v.w);
    ((ushort4*)out)[i] = o;
  }
}

__global__ void pad_w2(const float* __restrict__ w2, const float* __restrict__ b2,
                       ushort* __restrict__ w2p, float* __restrict__ b2p){
  int i = blockIdx.x*256 + threadIdx.x;
  int r = i >> 10, c = i & 1023;
  w2p[i] = (r < Cc) ? f2b(w2[r*1024 + c]) : (ushort)0;
  if (i < 1024) b2p[i] = (i < Cc) ? b2[i] : 0.f;
}

// ---------------- generic bf16 MFMA GEMM (m97 structure) ----------------

template<int RELU, int OUT_BF16>
__global__ __launch_bounds__(256) void gemm_bt(
    const ushort* __restrict__ A, const ushort* __restrict__ Bm,
    const float* __restrict__ bias, void* __restrict__ Cp,
    int M, int N, int K, int ldc, int nout)
{
  __shared__ ushort As[128*32];
  __shared__ ushort Bs[128*32];
  const int tid  = threadIdx.x;
  const int lane = tid & 63;
  const int wave = tid >> 6;
  const int wr = wave >> 1, wc = wave & 1;
  const int r0 = lane & 15, kg = lane >> 4;
  const int m0 = blockIdx.x*128, n0 = blockIdx.y*128;

  const ushort* aG = A  + (size_t)(m0 + (tid>>2))*K + (tid&3)*8;
  const ushort* bG = Bm + (size_t)(n0 + (tid>>2))*K + (tid&3)*8;
  ushort* aL = As + tid*8;
  ushort* bL = Bs + tid*8;
  const size_t rstep = (size_t)64*K;

  f32x4 acc[4][4] = {};

  for (int kt = 0; kt < K; kt += 32){
    __syncthreads();
    async16(aG + kt,         aL);
    async16(aG + kt + rstep, aL + 2048);
    async16(bG + kt,         bL);
    async16(bG + kt + rstep, bL + 2048);
    __syncthreads();
    bf16x8 af[4], bf_[4];
#pragma unroll
    for (int i=0;i<4;i++) af[i]  = *(const bf16x8*)&As[(wr*64 + i*16 + r0)*32 + kg*8];
#pragma unroll
    for (int j=0;j<4;j++) bf_[j] = *(const bf16x8*)&Bs[(wc*64 + j*16 + r0)*32 + kg*8];
#pragma unroll
    for (int i=0;i<4;i++)
#pragma unroll
      for (int j=0;j<4;j++)
        acc[i][j] = MFMA16(af[i], bf_[j], acc[i][j]);
  }

  const int rowb = m0 + wr*64 + kg*4;
  const int colb = n0 + wc*64 + r0;
#pragma unroll
  for (int i=0;i<4;i++){
#pragma unroll
    for (int j=0;j<4;j++){
      const int c = colb + j*16;
      if (c >= nout) continue;
      const float bv = bias ? bias[c] : 0.f;
#pragma unroll
      for (int q=0;q<4;q++){
        const int r = rowb + i*16 + q;
        float v = acc[i][j][q] + bv;
        if (RELU) v = fmaxf(v, 0.f);
        if (OUT_BF16) ((ushort*)Cp)[(size_t)r*ldc + c] = f2b(v);
        else          ((float* )Cp)[(size_t)r*ldc + c] = v;
      }
    }
  }
}

// ---------------- persistent GRU scan ----------------
// 64 WGs, WG g owns hidden units [g*16, g*16+16). W_hh K-slice per wave held in
// registers (24 bf16x8). h ping-pongs in global bf16; fp32 carry in registers.
// One device-scope barrier per timestep.

__global__ __launch_bounds__(256, 1) void gru_scan(
    const ushort* __restrict__ Whh, const float* __restrict__ bhh,
    const ushort* __restrict__ gx,
    ushort* __restrict__ hB,      // 2 * 32*1024 bf16 ping-pong (buf0 zeroed)
    ushort* __restrict__ hs,      // [B*T, H] bf16 out
    int* __restrict__ bar)        // zeroed counter
{
  __shared__ float red[4][2][3][256];
  const int g = blockIdx.x;
  const int tid = threadIdx.x;
  const int wave = tid >> 6, lane = tid & 63;
  const int r0 = lane & 15, kg = lane >> 4;
  const int k0 = wave*256 + kg*8;
  const int u  = tid & 15;          // hidden unit within group
  const int b0 = tid >> 4;          // batch 0..15 (pair: b0 and b0+16)
  const int jg = g*16 + u;

  // weight-stationary: this wave's K=256 slice of the 3 gate matrices
  bf16x8 wb[8][3];
  {
    const ushort* bB = Whh + ((size_t)(g*16 + r0))*1024 + k0;
#pragma unroll
    for (int s=0;s<8;s++){
      wb[s][0] = *(const bf16x8*)(bB + s*32);
      wb[s][1] = *(const bf16x8*)(bB + 1024*1024 + s*32);
      wb[s][2] = *(const bf16x8*)(bB + 2*1024*1024 + s*32);
    }
  }
  const float br = bhh[jg], bz = bhh[1024+jg], bn = bhh[2048+jg];
  float hold0 = 0.f, hold1 = 0.f;

  const int bi  = b0;                               // b0 & 15
  const int idx = ((bi>>2)*16 + u)*4 + (bi&3);      // red[] slot for (bi,u)

  for (int t = 0; t < Tt; ++t){
    const ushort* hin  = hB + (size_t)(t&1)*(Bb*Hh);
    ushort*       hout = hB + (size_t)((t+1)&1)*(Bb*Hh);

    // gx loads — independent of h, issue early
    const size_t row0 = (size_t)b0*Tt + t;
    const size_t row1 = (size_t)(b0+16)*Tt + t;
    const float xr0 = b2f(gx[row0*3072 + jg]);
    const float xz0 = b2f(gx[row0*3072 + 1024 + jg]);
    const float xn0 = b2f(gx[row0*3072 + 2048 + jg]);
    const float xr1 = b2f(gx[row1*3072 + jg]);
    const float xz1 = b2f(gx[row1*3072 + 1024 + jg]);
    const float xn1 = b2f(gx[row1*3072 + 2048 + jg]);

    f32x4 acc[2][3] = {};
    const ushort* aB = hin + r0*1024 + k0;
#pragma unroll
    for (int s=0;s<8;s++){
      bf16x8 a0 = *(const bf16x8*)(aB + s*32);
      bf16x8 a1 = *(const bf16x8*)(aB + 16*1024 + s*32);
      acc[0][0] = MFMA16(a0, wb[s][0], acc[0][0]);
      acc[0][1] = MFMA16(a0, wb[s][1], acc[0][1]);
      acc[0][2] = MFMA16(a0, wb[s][2], acc[0][2]);
      acc[1][0] = MFMA16(a1, wb[s][0], acc[1][0]);
      acc[1][1] = MFMA16(a1, wb[s][1], acc[1][1]);
      acc[1][2] = MFMA16(a1, wb[s][2], acc[1][2]);
    }
#pragma unroll
    for (int i=0;i<2;i++)
#pragma unroll
      for (int j=0;j<3;j++)
        *(f32x4*)&red[wave][i][j][lane*4] = acc[i][j];
    __syncthreads();

    float hr0=0,hz0=0,hn0=0, hr1=0,hz1=0,hn1=0;
#pragma unroll
    for (int w4=0; w4<4; ++w4){
      hr0 += red[w4][0][0][idx]; hz0 += red[w4][0][1][idx]; hn0 += red[w4][0][2][idx];
      hr1 += red[w4][1][0][idx]; hz1 += red[w4][1][1][idx]; hn1 += red[w4][1][2][idx];
    }
    {
      const float r = 1.f/(1.f + expf(-(xr0 + hr0 + br)));
      const float z = 1.f/(1.f + expf(-(xz0 + hz0 + bz)));
      const float n = tanhf(xn0 + r*(hn0 + bn));
      const float hnew = (1.f - z)*n + z*hold0;
      hold0 = hnew;
      const ushort hb = f2b(hnew);
      hout[b0*1024 + jg] = hb;
      hs[row0*1024 + jg] = hb;
    }
    {
      const float r = 1.f/(1.f + expf(-(xr1 + hr1 + br)));
      const float z = 1.f/(1.f + expf(-(xz1 + hz1 + bz)));
      const float n = tanhf(xn1 + r*(hn1 + bn));
      const float hnew = (1.f - z)*n + z*hold1;
      hold1 = hnew;
      const ushort hb = f2b(hnew);
      hout[(b0+16)*1024 + jg] = hb;
      hs[row1*1024 + jg] = hb;
    }

    if (t != Tt-1){
      // grid barrier: syncthreads drains vmcnt (stores in L2), tid0 release-adds
      __syncthreads();
      if (tid == 0){
        __hip_atomic_fetch_add(bar, 1, __ATOMIC_RELEASE, __HIP_MEMORY_SCOPE_AGENT);
        const int target = (t+1)*NWG;
        while (__hip_atomic_load(bar, __ATOMIC_ACQUIRE, __HIP_MEMORY_SCOPE_AGENT) < target)
          __builtin_amdgcn_s_sleep(2);
      }
      __syncthreads();
    }
  }
}

// ---------------- launch ----------------

extern "C" void kernel_launch(void* const* d_in, const int* in_sizes, int n_in,
                              void* d_out, int out_size, void* d_ws, size_t ws_size,
                              hipStream_t stream)
{
  const float* features = (const float*)d_in[0];
  const float* Wp  = (const float*)d_in[1];
  const float* bp  = (const float*)d_in[2];
  const float* Wih = (const float*)d_in[3];
  const float* bih = (const float*)d_in[4];
  const float* Whh = (const float*)d_in[5];
  const float* bhh = (const float*)d_in[6];
  const float* W1  = (const float*)d_in[7];
  const float* b1  = (const float*)d_in[8];
  const float* W2  = (const float*)d_in[9];
  const float* b2  = (const float*)d_in[10];
  float* out = (float*)d_out;

  char* w = (char*)d_ws;
  auto alloc = [&](size_t bytes){ char* p = w; w += (bytes + 255) & ~(size_t)255; return p; };
  ushort* fb   = (ushort*)alloc((size_t)Mm*Dd*2);
  ushort* xb   = (ushort*)alloc((size_t)Mm*Hh*2);
  ushort* gx   = (ushort*)alloc((size_t)Mm*3*Hh*2);
  ushort* hsb  = (ushort*)alloc((size_t)Mm*Hh*2);
  ushort* o1   = (ushort*)alloc((size_t)Mm*Hh*2);
  ushort* wpb  = (ushort*)alloc((size_t)Hh*Dd*2);
  ushort* wihb = (ushort*)alloc((size_t)3*Hh*Hh*2);
  ushort* whhb = (ushort*)alloc((size_t)3*Hh*Hh*2);
  ushort* w1b  = (ushort*)alloc((size_t)Hh*Hh*2);
  ushort* w2b  = (ushort*)alloc((size_t)1024*Hh*2);
  float*  b2p  = (float*)alloc(1024*4);
  ushort* hB   = (ushort*)alloc((size_t)2*Bb*Hh*2);
  int*    bar  = (int*)alloc(256);

  hipMemsetAsync(hB, 0, (size_t)2*Bb*Hh*2, stream);
  hipMemsetAsync(bar, 0, 256, stream);

  auto cvt = [&](const float* src, ushort* dst, size_t n){
    int n4 = (int)(n/4);
    hipLaunchKernelGGL(cvt_bf16, dim3((n4+255)/256), dim3(256), 0, stream, src, dst, n4);
  };
  cvt(features, fb, (size_t)Mm*Dd);
  cvt(Wp,  wpb,  (size_t)Hh*Dd);
  cvt(Wih, wihb, (size_t)3*Hh*Hh);
  cvt(Whh, whhb, (size_t)3*Hh*Hh);
  cvt(W1,  w1b,  (size_t)Hh*Hh);
  hipLaunchKernelGGL(pad_w2, dim3((1024*1024)/256), dim3(256), 0, stream, W2, b2, w2b, b2p);

  // x = relu(features @ Wp^T + bp)
  hipLaunchKernelGGL((gemm_bt<1,1>), dim3(Mm/128, Hh/128), dim3(256), 0, stream,
                     fb, wpb, bp, (void*)xb, Mm, Hh, Dd, Hh, Hh);
  // gx = x @ W_ih^T + b_ih
  hipLaunchKernelGGL((gemm_bt<0,1>), dim3(Mm/128, (3*Hh)/128), dim3(256), 0, stream,
                     xb, wihb, bih, (void*)gx, Mm, 3*Hh, Hh, 3*Hh, 3*Hh);

  // GRU scan: one persistent kernel, 512 internal steps
  hipLaunchKernelGGL(gru_scan, dim3(NWG), dim3(256), 0, stream,
                     whhb, bhh, gx, hB, hsb, bar);

  // out1 = relu(hs @ W1^T + b1)
  hipLaunchKernelGGL((gemm_bt<1,1>), dim3(Mm/128, Hh/128), dim3(256), 0, stream,
                     hsb, w1b, b1, (void*)o1, Mm, Hh, Hh, Hh, Hh);
  // out = out1 @ W2p^T + b2p  (store only first 1000 cols, fp32)
  hipLaunchKernelGGL((gemm_bt<0,0>), dim3(Mm/128, 1024/128), dim3(256), 0, stream,
                     o1, w2b, b2p, (void*)out, Mm, 1024, Hh, Cc, Cc);
}

// Round 3
// 2910.706 us; speedup vs baseline: 1.6520x; 1.5896x over previous
//
#include <hip/hip_runtime.h>
#include <hip/hip_bf16.h>
#include <stdint.h>

#define Bb 32
#define Tt 512
#define Dd 1024
#define Hh 1024
#define Cc 1000
#define Mm (Bb*Tt)
#define NWG 64

typedef float f32x4 __attribute__((ext_vector_type(4)));
typedef short bf16x8 __attribute__((ext_vector_type(8)));

#define MFMA16(a,b,c) __builtin_amdgcn_mfma_f32_16x16x32_bf16(a,b,c,0,0,0)

static __device__ __forceinline__ unsigned short f2b(float f){
  __hip_bfloat16 h = __float2bfloat16(f);
  union { __hip_bfloat16 h; unsigned short u; } cv; cv.h = h; return cv.u;
}
static __device__ __forceinline__ float b2f(unsigned short u){
  union { unsigned int i; float f; } cv; cv.i = ((unsigned int)u) << 16; return cv.f;
}

static __device__ __forceinline__ void async16(const ushort* g, ushort* l){
  __builtin_amdgcn_global_load_lds((const __attribute__((address_space(1))) unsigned int*)g,
                                   (__attribute__((address_space(3))) unsigned int*)l,
                                   16, 0, 0);
}

// coherent (cross-XCD visible, no cache-maintenance) 16B load / 4B store
static __device__ __forceinline__ bf16x8 load16cg(const ushort* p){
  bf16x8 r;
  asm volatile("global_load_dwordx4 %0, %1, off sc0 sc1" : "=v"(r) : "v"(p));
  return r;
}
static __device__ __forceinline__ void store4cg(ushort* p, unsigned int v){
  asm volatile("global_store_dword %0, %1, off sc0 sc1" :: "v"(p), "v"(v) : "memory");
}

// ---------------- conversion kernels ----------------

__global__ void cvt_bf16(const float* __restrict__ in, ushort* __restrict__ out, int n4){
  int i = blockIdx.x*256 + threadIdx.x;
  if (i < n4){
    const float4 v = ((const float4*)in)[i];
    ushort4 o;
    o.x = f2b(v.x); o.y = f2b(v.y); o.z = f2b(v.z); o.w = f2b(v.w);
    ((ushort4*)out)[i] = o;
  }
}

__global__ void pad_w2(const float* __restrict__ w2, const float* __restrict__ b2,
                       ushort* __restrict__ w2p, float* __restrict__ b2p){
  int i = blockIdx.x*256 + threadIdx.x;
  int r = i >> 10, c = i & 1023;
  w2p[i] = (r < Cc) ? f2b(w2[r*1024 + c]) : (ushort)0;
  if (i < 1024) b2p[i] = (i < Cc) ? b2[i] : 0.f;
}

// ---------------- generic bf16 MFMA GEMM (m97 structure) ----------------
// PERM_A: A stored row-permuted [t*32+b] for logical row m=b*512+t
// PERM_C: C stored row-permuted likewise

template<int RELU, int OUT_BF16, int PERM_A, int PERM_C>
__global__ __launch_bounds__(256) void gemm_bt(
    const ushort* __restrict__ A, const ushort* __restrict__ Bm,
    const float* __restrict__ bias, void* __restrict__ Cp,
    int M, int N, int K, int ldc, int nout)
{
  __shared__ ushort As[128*32];
  __shared__ ushort Bs[128*32];
  const int tid  = threadIdx.x;
  const int lane = tid & 63;
  const int wave = tid >> 6;
  const int wr = wave >> 1, wc = wave & 1;
  const int r0 = lane & 15, kg = lane >> 4;
  const int m0 = blockIdx.x*128, n0 = blockIdx.y*128;

  const int lrA0 = m0 + (tid>>2);
  const int lrA1 = lrA0 + 64;
  const size_t prA0 = PERM_A ? (size_t)((lrA0 & 511)*32 + (lrA0 >> 9)) : (size_t)lrA0;
  const size_t prA1 = PERM_A ? (size_t)((lrA1 & 511)*32 + (lrA1 >> 9)) : (size_t)lrA1;
  const ushort* aG0 = A  + prA0*K + (tid&3)*8;
  const ushort* aG1 = A  + prA1*K + (tid&3)*8;
  const ushort* bG  = Bm + (size_t)(n0 + (tid>>2))*K + (tid&3)*8;
  ushort* aL = As + tid*8;
  ushort* bL = Bs + tid*8;
  const size_t rstep = (size_t)64*K;

  f32x4 acc[4][4] = {};

  for (int kt = 0; kt < K; kt += 32){
    __syncthreads();
    async16(aG0 + kt, aL);
    async16(aG1 + kt, aL + 2048);
    async16(bG + kt,         bL);
    async16(bG + kt + rstep, bL + 2048);
    __syncthreads();
    bf16x8 af[4], bf_[4];
#pragma unroll
    for (int i=0;i<4;i++) af[i]  = *(const bf16x8*)&As[(wr*64 + i*16 + r0)*32 + kg*8];
#pragma unroll
    for (int j=0;j<4;j++) bf_[j] = *(const bf16x8*)&Bs[(wc*64 + j*16 + r0)*32 + kg*8];
#pragma unroll
    for (int i=0;i<4;i++)
#pragma unroll
      for (int j=0;j<4;j++)
        acc[i][j] = MFMA16(af[i], bf_[j], acc[i][j]);
  }

  const int rowb = m0 + wr*64 + kg*4;
  const int colb = n0 + wc*64 + r0;
#pragma unroll
  for (int i=0;i<4;i++){
#pragma unroll
    for (int j=0;j<4;j++){
      const int c = colb + j*16;
      if (c >= nout) continue;
      const float bv = bias ? bias[c] : 0.f;
#pragma unroll
      for (int q=0;q<4;q++){
        const int r = rowb + i*16 + q;
        const size_t pr = PERM_C ? (size_t)((r & 511)*32 + (r >> 9)) : (size_t)r;
        float v = acc[i][j][q] + bv;
        if (RELU) v = fmaxf(v, 0.f);
        if (OUT_BF16) ((ushort*)Cp)[pr*ldc + c] = f2b(v);
        else          ((float* )Cp)[pr*ldc + c] = v;
      }
    }
  }
}

// ---------------- persistent GRU scan ----------------
// 64 WGs, WG g owns hidden units [g*16, g*16+16). W_hh K-slice per wave pinned
// in VGPRs. h exchanged via coherent (sc0 sc1) loads/stores; relaxed-atomic
// barrier (no L2 flush/invalidate).

__global__ __launch_bounds__(256, 1) void gru_scan(
    const ushort* __restrict__ Whh, const float* __restrict__ bhh,
    const ushort* __restrict__ gxT,   // [t][b][3H]
    ushort* __restrict__ hB,          // 2 * 32*1024 bf16 ping-pong (buf0 zeroed)
    ushort* __restrict__ hsT,         // [t][b][H] bf16 out
    int* __restrict__ bar)            // zeroed counter
{
  __shared__ float red[4][2][3][256];
  const int g = blockIdx.x;
  const int tid = threadIdx.x;
  const int wave = tid >> 6, lane = tid & 63;
  const int r0 = lane & 15, kg = lane >> 4;
  const int k0 = wave*256 + kg*8;

  // weight-stationary: this wave's K=256 slice of the 3 gate matrices
  bf16x8 wb[8][3];
  {
    const ushort* bB = Whh + ((size_t)(g*16 + r0))*1024 + k0;
#pragma unroll
    for (int s=0;s<8;s++){
      wb[s][0] = *(const bf16x8*)(bB + s*32);
      wb[s][1] = *(const bf16x8*)(bB + 1024*1024 + s*32);
      wb[s][2] = *(const bf16x8*)(bB + 2*1024*1024 + s*32);
    }
  }
  // pin weights in VGPRs (prevent in-loop reloads)
#pragma unroll
  for (int s=0;s<8;s++)
#pragma unroll
    for (int j=0;j<3;j++)
      asm volatile("" : "+v"(wb[s][j]));

  // epilogue mapping: thread handles unit-pair up for batch b
  const int up = tid & 7;
  const int b  = tid >> 3;
  const int u0 = up*2;
  const int j0 = g*16 + u0;
  const float br0 = bhh[j0],        br1 = bhh[j0+1];
  const float bz0 = bhh[1024+j0],   bz1 = bhh[1024+j0+1];
  const float bn0 = bhh[2048+j0],   bn1 = bhh[2048+j0+1];
  float hold0 = 0.f, hold1 = 0.f;
  const int ii  = b >> 4, bi = b & 15;
  const int idx0 = ((bi>>2)*16 + u0)*4 + (bi&3);
  const int idx1 = ((bi>>2)*16 + u0+1)*4 + (bi&3);

  for (int t = 0; t < Tt; ++t){
    const ushort* hin  = hB + (size_t)(t&1)*(Bb*Hh);
    ushort*       hout = hB + (size_t)((t+1)&1)*(Bb*Hh);

    // gx loads — plain cached (read-only data), [t][b] layout is contiguous per step
    const ushort* gbase = gxT + (size_t)(t*32 + b)*3072;
    const unsigned int xr = *(const unsigned int*)(gbase + j0);
    const unsigned int xz = *(const unsigned int*)(gbase + 1024 + j0);
    const unsigned int xn = *(const unsigned int*)(gbase + 2048 + j0);

    // h loads: 16 coherent loads in flight, then one drain
    bf16x8 ha[8], hc[8];
    const ushort* aB = hin + r0*1024 + k0;
#pragma unroll
    for (int s=0;s<8;s++){
      ha[s] = load16cg(aB + s*32);
      hc[s] = load16cg(aB + 16*1024 + s*32);
    }
    asm volatile("s_waitcnt vmcnt(0)" ::: "memory");
    __builtin_amdgcn_sched_barrier(0);

    f32x4 acc[2][3] = {};
#pragma unroll
    for (int s=0;s<8;s++){
      acc[0][0] = MFMA16(ha[s], wb[s][0], acc[0][0]);
      acc[0][1] = MFMA16(ha[s], wb[s][1], acc[0][1]);
      acc[0][2] = MFMA16(ha[s], wb[s][2], acc[0][2]);
      acc[1][0] = MFMA16(hc[s], wb[s][0], acc[1][0]);
      acc[1][1] = MFMA16(hc[s], wb[s][1], acc[1][1]);
      acc[1][2] = MFMA16(hc[s], wb[s][2], acc[1][2]);
    }
#pragma unroll
    for (int i=0;i<2;i++)
#pragma unroll
      for (int j=0;j<3;j++)
        *(f32x4*)&red[wave][i][j][lane*4] = acc[i][j];
    __syncthreads();

    float hr0=0,hz0=0,hn0=0, hr1=0,hz1=0,hn1=0;
#pragma unroll
    for (int w4=0; w4<4; ++w4){
      hr0 += red[w4][ii][0][idx0]; hz0 += red[w4][ii][1][idx0]; hn0 += red[w4][ii][2][idx0];
      hr1 += red[w4][ii][0][idx1]; hz1 += red[w4][ii][1][idx1]; hn1 += red[w4][ii][2][idx1];
    }
    float hnew0, hnew1;
    {
      const float xrf = b2f((unsigned short)(xr & 0xffff));
      const float xzf = b2f((unsigned short)(xz & 0xffff));
      const float xnf = b2f((unsigned short)(xn & 0xffff));
      const float r = 1.f/(1.f + expf(-(xrf + hr0 + br0)));
      const float z = 1.f/(1.f + expf(-(xzf + hz0 + bz0)));
      const float n = tanhf(xnf + r*(hn0 + bn0));
      hnew0 = (1.f - z)*n + z*hold0;
      hold0 = hnew0;
    }
    {
      const float xrf = b2f((unsigned short)(xr >> 16));
      const float xzf = b2f((unsigned short)(xz >> 16));
      const float xnf = b2f((unsigned short)(xn >> 16));
      const float r = 1.f/(1.f + expf(-(xrf + hr1 + br1)));
      const float z = 1.f/(1.f + expf(-(xzf + hz1 + bz1)));
      const float n = tanhf(xnf + r*(hn1 + bn1));
      hnew1 = (1.f - z)*n + z*hold1;
      hold1 = hnew1;
    }
    const unsigned int packed = (unsigned int)f2b(hnew0) | ((unsigned int)f2b(hnew1) << 16);
    store4cg(hout + b*1024 + j0, packed);                       // coherent
    *(unsigned int*)(hsT + (size_t)(t*32 + b)*1024 + j0) = packed;  // plain streaming

    if (t != Tt-1){
      asm volatile("s_waitcnt vmcnt(0)" ::: "memory");
      __syncthreads();
      if (tid == 0){
        __hip_atomic_fetch_add(bar, 1, __ATOMIC_RELAXED, __HIP_MEMORY_SCOPE_AGENT);
        const int target = (t+1)*NWG;
        while (__hip_atomic_load(bar, __ATOMIC_RELAXED, __HIP_MEMORY_SCOPE_AGENT) < target)
          __builtin_amdgcn_s_sleep(8);
      }
      __syncthreads();
    }
  }
}

// ---------------- launch ----------------

extern "C" void kernel_launch(void* const* d_in, const int* in_sizes, int n_in,
                              void* d_out, int out_size, void* d_ws, size_t ws_size,
                              hipStream_t stream)
{
  const float* features = (const float*)d_in[0];
  const float* Wp  = (const float*)d_in[1];
  const float* bp  = (const float*)d_in[2];
  const float* Wih = (const float*)d_in[3];
  const float* bih = (const float*)d_in[4];
  const float* Whh = (const float*)d_in[5];
  const float* bhh = (const float*)d_in[6];
  const float* W1  = (const float*)d_in[7];
  const float* b1  = (const float*)d_in[8];
  const float* W2  = (const float*)d_in[9];
  const float* b2  = (const float*)d_in[10];
  float* out = (float*)d_out;

  char* w = (char*)d_ws;
  auto alloc = [&](size_t bytes){ char* p = w; w += (bytes + 255) & ~(size_t)255; return p; };
  ushort* fb   = (ushort*)alloc((size_t)Mm*Dd*2);
  ushort* xb   = (ushort*)alloc((size_t)Mm*Hh*2);
  ushort* gxT  = (ushort*)alloc((size_t)Mm*3*Hh*2);
  ushort* hsT  = (ushort*)alloc((size_t)Mm*Hh*2);
  ushort* o1   = (ushort*)alloc((size_t)Mm*Hh*2);
  ushort* wpb  = (ushort*)alloc((size_t)Hh*Dd*2);
  ushort* wihb = (ushort*)alloc((size_t)3*Hh*Hh*2);
  ushort* whhb = (ushort*)alloc((size_t)3*Hh*Hh*2);
  ushort* w1b  = (ushort*)alloc((size_t)Hh*Hh*2);
  ushort* w2b  = (ushort*)alloc((size_t)1024*Hh*2);
  float*  b2p  = (float*)alloc(1024*4);
  ushort* hB   = (ushort*)alloc((size_t)2*Bb*Hh*2);
  int*    bar  = (int*)alloc(256);

  hipMemsetAsync(hB, 0, (size_t)2*Bb*Hh*2, stream);
  hipMemsetAsync(bar, 0, 256, stream);

  auto cvt = [&](const float* src, ushort* dst, size_t n){
    int n4 = (int)(n/4);
    hipLaunchKernelGGL(cvt_bf16, dim3((n4+255)/256), dim3(256), 0, stream, src, dst, n4);
  };
  cvt(features, fb, (size_t)Mm*Dd);
  cvt(Wp,  wpb,  (size_t)Hh*Dd);
  cvt(Wih, wihb, (size_t)3*Hh*Hh);
  cvt(Whh, whhb, (size_t)3*Hh*Hh);
  cvt(W1,  w1b,  (size_t)Hh*Hh);
  hipLaunchKernelGGL(pad_w2, dim3((1024*1024)/256), dim3(256), 0, stream, W2, b2, w2b, b2p);

  // x = relu(features @ Wp^T + bp)
  hipLaunchKernelGGL((gemm_bt<1,1,0,0>), dim3(Mm/128, Hh/128), dim3(256), 0, stream,
                     fb, wpb, bp, (void*)xb, Mm, Hh, Dd, Hh, Hh);
  // gxT[t][b][:] = x @ W_ih^T + b_ih   (row-permuted C write)
  hipLaunchKernelGGL((gemm_bt<0,1,0,1>), dim3(Mm/128, (3*Hh)/128), dim3(256), 0, stream,
                     xb, wihb, bih, (void*)gxT, Mm, 3*Hh, Hh, 3*Hh, 3*Hh);

  // GRU scan: one persistent kernel, 512 internal steps
  hipLaunchKernelGGL(gru_scan, dim3(NWG), dim3(256), 0, stream,
                     whhb, bhh, gxT, hB, hsT, bar);

  // out1 = relu(hs @ W1^T + b1)  (row-permuted A read from hsT)
  hipLaunchKernelGGL((gemm_bt<1,1,1,0>), dim3(Mm/128, Hh/128), dim3(256), 0, stream,
                     hsT, w1b, b1, (void*)o1, Mm, Hh, Hh, Hh, Hh);
  // out = out1 @ W2p^T + b2p  (store only first 1000 cols, fp32)
  hipLaunchKernelGGL((gemm_bt<0,0,0,0>), dim3(Mm/128, 1024/128), dim3(256), 0, stream,
                     o1, w2b, b2p, (void*)out, Mm, 1024, Hh, Cc, Cc);
}